// Round 9
// baseline (113.870 us; speedup 1.0000x reference)
//
#include <hip/hip_runtime.h>

// CCN_2D on MI355X. N=256 vertices, K=16, C0=16, H=32.
// Facts (validated by exact passes R1-R8):
//  * CH rows one-hot => T_t[a][b][c] = Fin[j_t, P_t[a], P_t[b], c].
//  * A = I_16 collapses contract18 to 6 effective weight matrices.
//  * P_t[t] = -1 (no self-loops) => c17 / d_ttt terms vanish.
//  * Layer-1 input is broadcast of X => rank-1 closed form, no gathers.
//  * F1 channel-interleaved: chunk (i*16+q)*128 + c4*16 + p holds channels
//    4c4..4c4+3 of F1[i][p][q][:] (16 B stride on lane-varying p).
// R8 lesson: l2's ~65 KB of straight-line unrolled code >> 32 KB L1I ->
// frontend-bound (VALUBusy 20%, insensitive to waves). This round: l2
// rewritten with rolled readlane-matmuls (coef via stride-33 LDS),
// symmetric channel-half threads (one code path), E2 prep in a tiny
// kernel. l1 unchanged (its code already fits L1I).

constexpr int KN = 16, HH = 32, NV = 256, C2 = 32;

__device__ __forceinline__ float rlane(float v, int l) {
    return __int_as_float(__builtin_amdgcn_readlane(__float_as_int(v), l));
}

// ---- rolled half-matmul: acc[h] += sum_{k<16} cf[k] * Wg[k][h] ----
// Wg: 16 rows x 32 cols (512 floats, global); cfrow: 16 coefficients in LDS.
// Executed by full waves (readlane broadcast); B-loop rolled -> ~3.7 KB code.
__device__ __forceinline__ void mmrl16(const float* __restrict__ Wg,
                                       const float* cfrow, int lane,
                                       float* acc) {
    const float4 w0 = ((const float4*)Wg)[lane];
    const float4 w1 = ((const float4*)Wg)[64 + lane];
    #pragma unroll 1
    for (int B = 0; B < 2; ++B) {
        const float4 w_ = (B == 0) ? w0 : w1;
        float cf[8];
        #pragma unroll
        for (int cc = 0; cc < 8; ++cc) cf[cc] = cfrow[B * 8 + cc];
        #pragma unroll
        for (int cc = 0; cc < 8; ++cc) {
            #pragma unroll
            for (int h4 = 0; h4 < 8; ++h4) {
                const int src = 8 * cc + h4;
                acc[4*h4+0] = fmaf(cf[cc], rlane(w_.x, src), acc[4*h4+0]);
                acc[4*h4+1] = fmaf(cf[cc], rlane(w_.y, src), acc[4*h4+1]);
                acc[4*h4+2] = fmaf(cf[cc], rlane(w_.z, src), acc[4*h4+2]);
                acc[4*h4+3] = fmaf(cf[cc], rlane(w_.w, src), acc[4*h4+3]);
            }
        }
    }
}

// ---------------- prep: E2 effective weights -> ws ----------------
// slices (1024 f each): 0:Wsb 1:Wab 2:W16 3:Wt2 4:Wtb 5:Wal
__global__ __launch_bounds__(256)
void ccn_prep(const float* __restrict__ W2, float* __restrict__ E2g)
{
    const int u = blockIdx.x * 256 + threadIdx.x;   // 0..1023
    float acc = 0.f;
    #pragma unroll
    for (int g = 6; g < 15; ++g) acc += W2[g * 1024 + u];
    E2g[u]        = 16.f * W2[u] + W2[5 * 1024 + u] + 16.f * acc;
    E2g[1024 + u] = W2[1024 + u];
    E2g[2048 + u] = W2[15 * 1024 + u];
    E2g[3072 + u] = 16.f * W2[2 * 1024 + u];
    E2g[4096 + u] = W2[3 * 1024 + u];
    E2g[5120 + u] = W2[4 * 1024 + u];
}

// ---------------- layer 1 (unchanged from R8) ----------------
__global__ __launch_bounds__(512, 2)
void ccn_l1(const float* __restrict__ X, const int* __restrict__ nbrs,
            const float* __restrict__ W1, const float* __restrict__ bias,
            float* __restrict__ F1c, float* __restrict__ outz)
{
    __shared__ float sE1[6 * 512];
    __shared__ float sPP[256 * 36];
    __shared__ float sX[16][20];
    __shared__ float sV[16][164];
    __shared__ int   s_nbi[16];
    __shared__ int   s_nbj[16][17];
    __shared__ int   s_P[16][16];
    __shared__ int   s_vm[16];
    __shared__ float s_m[16];

    const int tid  = threadIdx.x;
    const int i    = ((blockIdx.x & 7) << 5) | (blockIdx.x >> 3);
    const int lane = tid & 63;

    if (blockIdx.x == 0 && tid == 0) outz[0] = 0.f;
    if (tid < 16) s_nbi[tid] = nbrs[i * 16 + tid];
    __syncthreads();

    if (tid < 256) {
        const int t = tid >> 4, y = tid & 15;
        const int j = s_nbi[t];
        s_nbj[t][y] = nbrs[j * 16 + y];
        sX[t][y]    = X[j * 16 + y];
    } else {
        const int u = tid - 256;
        float acc = 0.f;
        #pragma unroll
        for (int g = 6; g < 15; ++g) acc += W1[g * 512 + u];
        sE1[u]        = 16.f * W1[u] + W1[5 * 512 + u] + 16.f * acc;
        sE1[512 + u]  = W1[512 + u];
        sE1[1024 + u] = W1[15 * 512 + u];
        sE1[1536 + u] = 16.f * W1[2 * 512 + u];
        sE1[2048 + u] = W1[3 * 512 + u];
        sE1[2560 + u] = W1[4 * 512 + u];
    }
    __syncthreads();

    if (tid < 256) {
        const int t = tid >> 4, y = tid & 15;
        const int tgt = s_nbi[y];
        int p = -1;
        #pragma unroll
        for (int q = 0; q < 16; ++q) if (s_nbj[t][q] == tgt) p = q;
        s_P[t][y] = p;
        unsigned long long bal = __ballot(p >= 0);
        if (y == 0) {
            int vm = (int)((bal >> ((t & 3) * 16)) & 0xFFFFull);
            s_vm[t] = vm;
            s_m[t]  = (float)__popc(vm);
        }
    } else {
        const int u = tid;
        float acc = 0.f;
        #pragma unroll
        for (int g = 6; g < 15; ++g) acc += W1[g * 512 + u];
        sE1[u]        = 16.f * W1[u] + W1[5 * 512 + u] + 16.f * acc;
        sE1[512 + u]  = W1[512 + u];
        sE1[1024 + u] = W1[15 * 512 + u];
        sE1[1536 + u] = 16.f * W1[2 * 512 + u];
        sE1[2048 + u] = W1[3 * 512 + u];
        sE1[2560 + u] = W1[4 * 512 + u];
    }
    __syncthreads();

    if (tid < 256) {
        const int t = tid >> 4, y = tid & 15, x = t;
        float Y0[16];
        #pragma unroll
        for (int c4 = 0; c4 < 4; ++c4) {
            float4 v = *(const float4*)&sX[t][4 * c4];
            Y0[4*c4+0] = v.x; Y0[4*c4+1] = v.y; Y0[4*c4+2] = v.z; Y0[4*c4+3] = v.w;
        }
        float Z4[16], Z5[16];
        #pragma unroll
        for (int c = 0; c < 16; ++c) { Z4[c] = 0.f; Z5[c] = 0.f; }
        #pragma unroll
        for (int tp = 0; tp < 16; ++tp) {
            const int vm = s_vm[tp];
            const float mt = s_m[tp];
            const float fb = ((vm >> x) & 1) ? mt : 0.f;
            const float f5 = mt * mt;
            #pragma unroll
            for (int c4 = 0; c4 < 4; ++c4) {
                float4 v = *(const float4*)&sX[tp][4 * c4];
                Z4[4*c4+0] = fmaf(fb, v.x, Z4[4*c4+0]);
                Z4[4*c4+1] = fmaf(fb, v.y, Z4[4*c4+1]);
                Z4[4*c4+2] = fmaf(fb, v.z, Z4[4*c4+2]);
                Z4[4*c4+3] = fmaf(fb, v.w, Z4[4*c4+3]);
                Z5[4*c4+0] = fmaf(f5, v.x, Z5[4*c4+0]);
                Z5[4*c4+1] = fmaf(f5, v.y, Z5[4*c4+1]);
                Z5[4*c4+2] = fmaf(f5, v.z, Z5[4*c4+2]);
                Z5[4*c4+3] = fmaf(f5, v.w, Z5[4*c4+3]);
            }
        }
        const float m = s_m[t];
        float v0a=0.f,v0b=0.f,v1a=0.f,v1b=0.f,v2a=0.f,v2b=0.f;
        float v3a=0.f,v3b=0.f,v4a=0.f,v4b=0.f;
        const float2* Wsb = (const float2*)(sE1 + 0 * 512);
        const float2* Wab = (const float2*)(sE1 + 1 * 512);
        const float2* W16 = (const float2*)(sE1 + 2 * 512);
        const float2* Wtb = (const float2*)(sE1 + 4 * 512);
        const float2* Wal = (const float2*)(sE1 + 5 * 512);
        #pragma unroll
        for (int c = 0; c < 16; ++c) {
            const float cf0 = m * Y0[c];
            const float cf1 = m * cf0;
            const float cf2 = Y0[c];
            const float cf3 = Z4[c];
            const float cf4 = Z5[c];
            const int idx = c * 16 + y;
            float2 w0 = Wsb[idx]; v0a = fmaf(cf0, w0.x, v0a); v0b = fmaf(cf0, w0.y, v0b);
            float2 w1 = Wab[idx]; v1a = fmaf(cf1, w1.x, v1a); v1b = fmaf(cf1, w1.y, v1b);
            float2 w2 = W16[idx]; v2a = fmaf(cf2, w2.x, v2a); v2b = fmaf(cf2, w2.y, v2b);
            float2 w3 = Wtb[idx]; v3a = fmaf(cf3, w3.x, v3a); v3b = fmaf(cf3, w3.y, v3b);
            float2 w4 = Wal[idx]; v4a = fmaf(cf4, w4.x, v4a); v4b = fmaf(cf4, w4.y, v4b);
        }
        *(float2*)&sV[t][0 * 32 + 2 * y] = make_float2(v0a, v0b);
        *(float2*)&sV[t][1 * 32 + 2 * y] = make_float2(v1a, v1b);
        *(float2*)&sV[t][2 * 32 + 2 * y] = make_float2(v2a, v2b);
        *(float2*)&sV[t][3 * 32 + 2 * y] = make_float2(v3a, v3b);
        *(float2*)&sV[t][4 * 32 + 2 * y] = make_float2(v4a, v4b);
    } else {
        const int w = tid - 256;
        const int t = w >> 4, y = w & 15, x = t;
        float Z2[16];
        #pragma unroll
        for (int c = 0; c < 16; ++c) Z2[c] = 0.f;
        #pragma unroll
        for (int tp = 0; tp < 16; ++tp) {
            const int vm = s_vm[tp];
            const float f2 = (float)((vm >> x) & (vm >> y) & 1);
            #pragma unroll
            for (int c4 = 0; c4 < 4; ++c4) {
                float4 v = *(const float4*)&sX[tp][4 * c4];
                Z2[4*c4+0] = fmaf(f2, v.x, Z2[4*c4+0]);
                Z2[4*c4+1] = fmaf(f2, v.y, Z2[4*c4+1]);
                Z2[4*c4+2] = fmaf(f2, v.z, Z2[4*c4+2]);
                Z2[4*c4+3] = fmaf(f2, v.w, Z2[4*c4+3]);
            }
        }
        float pp[HH];
        #pragma unroll
        for (int h = 0; h < HH; ++h) pp[h] = 0.f;
        // unrolled NB=2 readlane matmul (Wt2 = sE1 slice 3)
        {
            const float* Wp = sE1 + 3 * 512;
            #pragma unroll
            for (int B = 0; B < 2; ++B) {
                const float4 w_ = ((const float4*)Wp)[B * 64 + lane];
                #pragma unroll
                for (int cc = 0; cc < 8; ++cc) {
                    const float cf_ = Z2[B * 8 + cc];
                    #pragma unroll
                    for (int h4 = 0; h4 < 8; ++h4) {
                        const int src_ = 8 * cc + h4;
                        pp[4*h4+0] = fmaf(cf_, rlane(w_.x, src_), pp[4*h4+0]);
                        pp[4*h4+1] = fmaf(cf_, rlane(w_.y, src_), pp[4*h4+1]);
                        pp[4*h4+2] = fmaf(cf_, rlane(w_.z, src_), pp[4*h4+2]);
                        pp[4*h4+3] = fmaf(cf_, rlane(w_.w, src_), pp[4*h4+3]);
                    }
                }
            }
        }
        float* dst = &sPP[(t * 16 + y) * 36];
        #pragma unroll
        for (int h4 = 0; h4 < 8; ++h4)
            *(float4*)&dst[4 * h4] = make_float4(pp[4*h4], pp[4*h4+1], pp[4*h4+2], pp[4*h4+3]);
    }
    __syncthreads();

    float fr[HH];
    if (tid < 256) {
        const int t = tid >> 4, y = tid & 15, x = t;
        const float vy  = (s_P[t][y] >= 0) ? 1.f : 0.f;
        const float dxy = (x == y) ? 1.f : 0.f;
        const float* pp = &sPP[(t * 16 + y) * 36];
        #pragma unroll
        for (int h4 = 0; h4 < 8; ++h4) {
            const float4 V0 = *(const float4*)&sV[t][0 * 32 + 4 * h4];
            const float4 V1 = *(const float4*)&sV[t][1 * 32 + 4 * h4];
            const float4 V2 = *(const float4*)&sV[t][2 * 32 + 4 * h4];
            const float4 V3 = *(const float4*)&sV[t][3 * 32 + 4 * h4];
            const float4 V4 = *(const float4*)&sV[t][4 * 32 + 4 * h4];
            const float4 PP = *(const float4*)&pp[4 * h4];
            float a_ = vy*(V0.x+V2.x) + V1.x + V3.x + dxy*V4.x + PP.x + bias[4*h4+0];
            float b_ = vy*(V0.y+V2.y) + V1.y + V3.y + dxy*V4.y + PP.y + bias[4*h4+1];
            float c_ = vy*(V0.z+V2.z) + V1.z + V3.z + dxy*V4.z + PP.z + bias[4*h4+2];
            float d_ = vy*(V0.w+V2.w) + V1.w + V3.w + dxy*V4.w + PP.w + bias[4*h4+3];
            fr[4*h4+0] = a_ > 0.f ? a_ : 0.f;
            fr[4*h4+1] = b_ > 0.f ? b_ : 0.f;
            fr[4*h4+2] = c_ > 0.f ? c_ : 0.f;
            fr[4*h4+3] = d_ > 0.f ? d_ : 0.f;
        }
    }
    __syncthreads();

    if (tid < 256) {
        const int t = tid >> 4, y = tid & 15;
        float* dst = &sPP[(y * 16 + t) * 36];
        #pragma unroll
        for (int h4 = 0; h4 < 8; ++h4)
            *(float4*)&dst[4 * h4] = make_float4(fr[4*h4], fr[4*h4+1], fr[4*h4+2], fr[4*h4+3]);
    }
    __syncthreads();

    if (tid < 256) {
        const int q = tid >> 4, p = tid & 15;
        const float* src = &sPP[(q * 16 + p) * 36];
        float4* F4 = (float4*)F1c;
        const size_t basec = ((size_t)i * 16 + q) * 128 + p;
        #pragma unroll
        for (int c4 = 0; c4 < 8; ++c4)
            F4[basec + c4 * 16] = *(const float4*)&src[4 * c4];
    }
}

// ---------------- layer 2: symmetric channel-half threads ----------------
// thread (cell = t*16+y, h) owns channels [16h, 16h+16). Wave-uniform h.
__global__ __launch_bounds__(512, 2)
void ccn_l2(const float* __restrict__ F1c, const int* __restrict__ nbrs,
            const float* __restrict__ E2g, const float* __restrict__ bias,
            const float* __restrict__ fcw, const float* __restrict__ fcb,
            float* __restrict__ out)
{
    __shared__ float sCf[256 * 33];     // 33 KB: stride-33 coef/park buffer
    __shared__ float s_stb[16 * 33];
    __shared__ float s_sall[32];
    __shared__ float sMv[2][16][68];    // matvec partials [h][t][S:0..31|L:32..63]
    __shared__ int   s_nbi[16];
    __shared__ int   s_PQ[16 * 17];
    __shared__ float s_red[4];

    const int tid  = threadIdx.x;
    const int i    = ((blockIdx.x & 7) << 5) | (blockIdx.x >> 3);
    const int lane = tid & 63;
    const int h    = tid >> 8;          // 0/1, wave-uniform
    const int cell = tid & 255;
    const int t = cell >> 4, y = cell & 15;
    const int hc = 4 * h;               // chunk base of my channel half
    const float4* F4 = (const float4*)F1c;

    if (tid < 16) s_nbi[tid] = nbrs[i * 16 + tid];
    __syncthreads();                                     // b0
    if (tid < 256) s_PQ[t * 17 + y] = nbrs[s_nbi[t] * 16 + y];
    __syncthreads();                                     // b1
    if (tid < 256) {
        const int tgt = s_nbi[y];
        int p = -1;
        #pragma unroll
        for (int q = 0; q < 16; ++q) if (s_PQ[t * 17 + q] == tgt) p = q;
        s_PQ[t * 17 + y] = p;
    }
    __syncthreads();                                     // b2

    const int j = s_nbi[t];
    const int p = s_PQ[t * 17 + y];
    const float mp = (p >= 0) ? 1.f : 0.f;
    const int pc = p >= 0 ? p : 0;
    const size_t jbase = (size_t)j * 2048;
    float* myrow = &sCf[cell * 33 + 16 * h];

    // ---- R gather (own cell, my 16 channels); fully unrolled for load batching
    float R16[16];
    #pragma unroll
    for (int k = 0; k < 16; ++k) R16[k] = 0.f;
    #pragma unroll
    for (int b = 0; b < 16; ++b) {
        const int q = s_PQ[t * 17 + b];
        const float mm = (q >= 0) ? mp : 0.f;
        const int qc = q >= 0 ? q : 0;
        const size_t rb = jbase + (size_t)qc * 128 + hc * 16 + pc;
        #pragma unroll
        for (int k = 0; k < 4; ++k) {
            float4 v = F4[rb + k * 16];
            R16[4*k+0] = fmaf(mm, v.x, R16[4*k+0]);
            R16[4*k+1] = fmaf(mm, v.y, R16[4*k+1]);
            R16[4*k+2] = fmaf(mm, v.z, R16[4*k+2]);
            R16[4*k+3] = fmaf(mm, v.w, R16[4*k+3]);
        }
    }
    float sab16[16];
    #pragma unroll
    for (int k = 0; k < 16; ++k) {
        float s = R16[k];
        s += __shfl_xor(s, 1); s += __shfl_xor(s, 2);
        s += __shfl_xor(s, 4); s += __shfl_xor(s, 8);
        sab16[k] = s;
    }
    #pragma unroll
    for (int k = 0; k < 16; ++k) myrow[k] = R16[k];
    __syncthreads();                                     // b3 (R rows ready)

    // ---- Wsb half-matmul + stb reduction (both read-only on sCf) ----
    float pre[32];
    #pragma unroll
    for (int k = 0; k < 32; ++k) pre[k] = 0.f;
    mmrl16(E2g + 0 * 1024 + h * 512, myrow, lane, pre);  // Wsb
    {
        const int x2 = tid >> 5, c = tid & 31;           // 512 outputs, 1/thread
        float s = 0.f;
        #pragma unroll 4
        for (int tt = 0; tt < 16; ++tt) s += sCf[(tt * 16 + x2) * 33 + c];
        s_stb[x2 * 33 + c] = s;
    }
    __syncthreads();                                     // b4 (stb done; R rows free)

    if (tid < 32) {
        float s = 0.f;
        #pragma unroll
        for (int x2 = 0; x2 < 16; ++x2) s += s_stb[x2 * 33 + tid];
        s_sall[tid] = s;
    }
    // ---- ST gather for TRANSPOSED cell (x=y, y_out=t): p-slot lane-varying
    float ST16[16];
    #pragma unroll
    for (int k = 0; k < 16; ++k) ST16[k] = 0.f;
    #pragma unroll
    for (int tp = 0; tp < 16; ++tp) {
        const int jt = s_nbi[tp];
        const int px = s_PQ[tp * 17 + y];                // lane-varying
        const int pq = s_PQ[tp * 17 + t];                // group-uniform
        const float mm = (px >= 0 && pq >= 0) ? 1.f : 0.f;
        const int pxc = px >= 0 ? px : 0;
        const int pqc = pq >= 0 ? pq : 0;
        const size_t rb = (size_t)jt * 2048 + (size_t)pqc * 128 + hc * 16 + pxc;
        #pragma unroll
        for (int k = 0; k < 4; ++k) {
            float4 v = F4[rb + k * 16];
            ST16[4*k+0] = fmaf(mm, v.x, ST16[4*k+0]);
            ST16[4*k+1] = fmaf(mm, v.y, ST16[4*k+1]);
            ST16[4*k+2] = fmaf(mm, v.z, ST16[4*k+2]);
            ST16[4*k+3] = fmaf(mm, v.w, ST16[4*k+3]);
        }
    }
    // own-row round trips (same-thread ordered; no barriers needed)
    float preT[32];
    #pragma unroll
    for (int k = 0; k < 32; ++k) preT[k] = 0.f;
    #pragma unroll
    for (int k = 0; k < 16; ++k) myrow[k] = ST16[k];
    mmrl16(E2g + 3 * 1024 + h * 512, myrow, lane, preT); // Wt2 (transposed cell)
    {   // D = diag row (own cell)
        const size_t db = jbase + (size_t)pc * 128 + hc * 16 + pc;
        #pragma unroll
        for (int k = 0; k < 4; ++k) {
            float4 v = F4[db + k * 16];
            myrow[4*k+0] = mp * v.x; myrow[4*k+1] = mp * v.y;
            myrow[4*k+2] = mp * v.z; myrow[4*k+3] = mp * v.w;
        }
    }
    mmrl16(E2g + 2 * 1024 + h * 512, myrow, lane, pre);  // W16 (own cell)
    #pragma unroll
    for (int k = 0; k < 16; ++k) myrow[k] = sab16[k];
    __syncthreads();                                     // b5 (s_sall ready)

    // ---- cooperative matvecs (Wab/Wtb/Wal), split by channel half ----
    {
        float S0 = 0.f, S1 = 0.f, L0 = 0.f, L1 = 0.f;
        const float2* Wab = (const float2*)(E2g + 1 * 1024);
        const float2* Wtb = (const float2*)(E2g + 4 * 1024);
        const float2* Wal = (const float2*)(E2g + 5 * 1024);
        #pragma unroll 4
        for (int k = 0; k < 16; ++k) {
            const int c = 16 * h + k;
            const float cfa = myrow[k];                  // sab
            const float cft = s_stb[t * 33 + c];
            const float cfl = s_sall[c];
            const float2 wa = Wab[c * 16 + y];
            const float2 wt = Wtb[c * 16 + y];
            const float2 wl = Wal[c * 16 + y];
            S0 += cfa * wa.x + cft * wt.x;
            S1 += cfa * wa.y + cft * wt.y;
            L0 += cfl * wl.x;
            L1 += cfl * wl.y;
        }
        sMv[h][t][2 * y]      = S0;
        sMv[h][t][2 * y + 1]  = S1;
        sMv[h][t][32 + 2 * y] = L0;
        sMv[h][t][33 + 2 * y] = L1;
    }
    __syncthreads();                                     // b6

    // ---- park dance: combine Wt2 (transposed) + h-halves ----
    const int rT = y * 16 + t;
    if (h == 0) {
        #pragma unroll
        for (int k = 0; k < 32; ++k) sCf[rT * 33 + k] = preT[k];
    }
    __syncthreads();                                     // b7
    if (h == 1) {
        #pragma unroll
        for (int k = 0; k < 32; ++k) sCf[rT * 33 + k] += preT[k];
    }
    __syncthreads();                                     // b8
    if (h == 0) {
        #pragma unroll
        for (int k = 0; k < 32; ++k) pre[k] += sCf[cell * 33 + k];  // full Wt2 term
    }
    __syncthreads();                                     // b9
    if (h == 1) {
        #pragma unroll
        for (int k = 0; k < 32; ++k) sCf[cell * 33 + k] = pre[k];   // park h1 Wsb+W16
    }
    __syncthreads();                                     // b10

    if (h == 0) {
        #pragma unroll
        for (int k = 0; k < 32; ++k) pre[k] += sCf[cell * 33 + k];
        const float dxy = (t == y) ? 1.f : 0.f;
        float local = 0.f;
        #pragma unroll
        for (int k = 0; k < 32; ++k) {
            const float S = sMv[0][t][k]      + sMv[1][t][k];
            const float L = sMv[0][t][32 + k] + sMv[1][t][32 + k];
            float v = pre[k] + S + dxy * L + bias[k];
            v = v > 0.f ? v : 0.f;
            local += v * fcw[k];
        }
        #pragma unroll
        for (int off = 32; off > 0; off >>= 1) local += __shfl_down(local, off, 64);
        if (lane == 0) s_red[tid >> 6] = local;
    }
    __syncthreads();                                     // b11
    if (tid == 0) {
        atomicAdd(out, s_red[0] + s_red[1] + s_red[2] + s_red[3]
                       + fcb[0] * (1.f / 256.f));
    }
}

extern "C" void kernel_launch(void* const* d_in, const int* in_sizes, int n_in,
                              void* d_out, int out_size, void* d_ws, size_t ws_size,
                              hipStream_t stream) {
    const float* X    = (const float*)d_in[0];
    const int*   nbrs = (const int*)  d_in[1];
    const float* W1   = (const float*)d_in[2];
    const float* b1   = (const float*)d_in[3];
    const float* W2   = (const float*)d_in[4];
    const float* b2   = (const float*)d_in[5];
    const float* fc_w = (const float*)d_in[6];
    const float* fc_b = (const float*)d_in[7];
    float* outp = (float*)d_out;

    float* F1c = (float*)d_ws;                            // 8 MB
    float* E2g = F1c + (size_t)NV * KN * KN * HH;         // 6144 floats

    ccn_prep<<<4, 256, 0, stream>>>(W2, E2g);
    ccn_l1<<<NV, 512, 0, stream>>>(X, nbrs, W1, b1, F1c, outp);
    ccn_l2<<<NV, 512, 0, stream>>>(F1c, nbrs, E2g, b2, fc_w, fc_b, outp);
}